// Round 4
// baseline (476.205 us; speedup 1.0000x reference)
//
#include <hip/hip_runtime.h>
#include <hip/hip_fp16.h>

#define SEQ 23
#define DIM 10
#define TPB 12                 // threads per batch (thread t owns rows t and t+12)
#define BPB 21                 // batches per block (21*12 = 252 of 256 threads)
#define NTHR 256
#define NROW (BPB * SEQ)       // 483 real rows + 1 dummy

typedef _Float16 hf2 __attribute__((ext_vector_type(2)));

static __device__ __forceinline__ float fdot2(hf2 a, hf2 b, float c) {
#if __has_builtin(__builtin_amdgcn_fdot2)
    return __builtin_amdgcn_fdot2(a, b, c, false);
#else
    return c + (float)a[0] * (float)b[0] + (float)a[1] * (float)b[1];
#endif
}
static __device__ __forceinline__ float fastexp2(float x) {
#if __has_builtin(__builtin_amdgcn_exp2f)
    return __builtin_amdgcn_exp2f(x);
#else
    return exp2f(x);
#endif
}
static __device__ __forceinline__ unsigned pack2(float a, float b) {
    __half2 h = __floats2half2_rn(a, b);   // v_cvt_pkrtz_f16_f32
    return __builtin_bit_cast(unsigned, h);
}
static __device__ __forceinline__ hf2 u2h(unsigned u) {
    return __builtin_bit_cast(hf2, u);
}
static __device__ __forceinline__ __half2 u2hh(unsigned u) {
    return __builtin_bit_cast(__half2, u);
}
static __device__ __forceinline__ hf2 h2f(__half2 h) {
    return __builtin_bit_cast(hf2, h);
}

// ---- prep: ws[a*5+p]    = half2(MT[a][2p], MT[a][2p+1]),  MT = (sc)*M^T,
//                           M = Wq^T Wk, sc = (1/sqrt(10))*log2(e)
//      ws[50+e*5+p] = half2(Wv[e][2p], Wv[e][2p+1])
__global__ void attn_prep_kernel(const float* __restrict__ Wk,
                                 const float* __restrict__ Wq,
                                 const float* __restrict__ Wv,
                                 unsigned* __restrict__ ws) {
    const int t = threadIdx.x;
    if (t < 50) {
        const int a = t / 5, p = t % 5;   // a = col of M (row of MT), d = 2p,2p+1
        float m0 = 0.f, m1 = 0.f;
        #pragma unroll
        for (int k = 0; k < 10; ++k) {
            m0 += Wq[k * 10 + 2 * p]     * Wk[k * 10 + a];
            m1 += Wq[k * 10 + 2 * p + 1] * Wk[k * 10 + a];
        }
        const float sc = 0.31622776601683794f * 1.44269504088896340f;
        ws[t] = pack2(m0 * sc, m1 * sc);
    } else if (t < 100) {
        const int e = (t - 50) / 5, p = (t - 50) % 5;
        ws[t] = pack2(Wv[e * 10 + 2 * p], Wv[e * 10 + 2 * p + 1]);
    }
}

__global__ __launch_bounds__(NTHR, 4) void attn_main_kernel(
    const float* __restrict__ x,      // [B][23][10] f32
    const unsigned* __restrict__ wsu, // packed weights (uniform -> s_load)
    float* __restrict__ out,          // [B][230] f32
    int B)
{
    // x rows in f16 pairs, 32B stride (b128 + b32 per row); +1 dummy row
    __shared__ __align__(16) unsigned xb[NROW + 1][8];

    const int tid = threadIdx.x;
    const int bl  = tid / TPB;
    const int t   = tid - bl * TPB;
    const long b  = (long)blockIdx.x * BPB + bl;
    const bool act  = (tid < BPB * TPB) && (b < (long)B);
    const bool hasB = act && (t < TPB - 1);   // row t+12 valid only for t<11

    const int rA = t, rB = t + TPB;

    float xrA[DIM], xrB[DIM];
    hf2   xpA[5], xpB[5];
    unsigned upA[5], upB[5];   // u' = MT x  (f16 pairs, stays in registers)

    if (act) {
        const float* pa = x + (b * SEQ + rA) * DIM;
        const float* pb = x + (b * SEQ + (hasB ? rB : rA)) * DIM;
        #pragma unroll
        for (int p = 0; p < 5; ++p) {
            float2 ta = *reinterpret_cast<const float2*>(pa + 2 * p);
            float2 tb = *reinterpret_cast<const float2*>(pb + 2 * p);
            xrA[2 * p] = ta.x; xrA[2 * p + 1] = ta.y;
            xrB[2 * p] = tb.x; xrB[2 * p + 1] = tb.y;
            xpA[p] = u2h(pack2(ta.x, ta.y));
            xpB[p] = u2h(pack2(tb.x, tb.y));
        }
        // stage x rows to LDS (t=11's second row goes to the dummy slot)
        const int rowA = bl * SEQ + rA;
        const int rowB = hasB ? (bl * SEQ + rB) : NROW;
        *reinterpret_cast<uint4*>(&xb[rowA][0]) = make_uint4(
            __builtin_bit_cast(unsigned, xpA[0]), __builtin_bit_cast(unsigned, xpA[1]),
            __builtin_bit_cast(unsigned, xpA[2]), __builtin_bit_cast(unsigned, xpA[3]));
        xb[rowA][4] = __builtin_bit_cast(unsigned, xpA[4]);
        *reinterpret_cast<uint4*>(&xb[rowB][0]) = make_uint4(
            __builtin_bit_cast(unsigned, xpB[0]), __builtin_bit_cast(unsigned, xpB[1]),
            __builtin_bit_cast(unsigned, xpB[2]), __builtin_bit_cast(unsigned, xpB[3]));
        xb[rowB][4] = __builtin_bit_cast(unsigned, xpB[4]);

        // u' projections (scalar-loaded MT), in registers
        #pragma unroll
        for (int q = 0; q < 5; ++q) {
            float a0 = 0.f, a1 = 0.f, b0 = 0.f, b1 = 0.f;
            #pragma unroll
            for (int p = 0; p < 5; ++p) {
                const hf2 m0 = u2h(wsu[(2 * q) * 5 + p]);
                const hf2 m1 = u2h(wsu[(2 * q + 1) * 5 + p]);
                a0 = fdot2(xpA[p], m0, a0);
                a1 = fdot2(xpA[p], m1, a1);
                b0 = fdot2(xpB[p], m0, b0);
                b1 = fdot2(xpB[p], m1, b1);
            }
            upA[q] = pack2(a0, a1);
            upB[q] = pack2(b0, b1);
        }
    }
    __syncthreads();
    if (!act) return;

    const unsigned (*xrow)[8] = &xb[bl * SEQ];

    // ---- logits for both rows (log2 units): s[j] = u' . x_j ----
    float sA[SEQ], sB[SEQ];
    #pragma unroll
    for (int j = 0; j < SEQ; ++j) {
        uint4 q4 = *reinterpret_cast<const uint4*>(&xrow[j][0]);
        unsigned q1 = xrow[j][4];
        float a = fdot2(u2h(upA[0]), u2h(q4.x), 0.f);
        a = fdot2(u2h(upA[1]), u2h(q4.y), a);
        a = fdot2(u2h(upA[2]), u2h(q4.z), a);
        a = fdot2(u2h(upA[3]), u2h(q4.w), a);
        a = fdot2(u2h(upA[4]), u2h(q1),   a);
        sA[j] = a;
        float c = fdot2(u2h(upB[0]), u2h(q4.x), 0.f);
        c = fdot2(u2h(upB[1]), u2h(q4.y), c);
        c = fdot2(u2h(upB[2]), u2h(q4.z), c);
        c = fdot2(u2h(upB[3]), u2h(q4.w), c);
        c = fdot2(u2h(upB[4]), u2h(q1),   c);
        sB[j] = c;
    }

    // ---- max via 3-way trees ----
#define F3(a, b, c) fmaxf(fmaxf((a), (b)), (c))
    float mA, mB;
    {
        const float t0 = F3(sA[0], sA[1], sA[2]),   t1 = F3(sA[3], sA[4], sA[5]);
        const float t2 = F3(sA[6], sA[7], sA[8]),   t3 = F3(sA[9], sA[10], sA[11]);
        const float t4 = F3(sA[12], sA[13], sA[14]), t5 = F3(sA[15], sA[16], sA[17]);
        const float t6 = F3(sA[18], sA[19], sA[20]), t7 = fmaxf(sA[21], sA[22]);
        mA = F3(F3(t0, t1, t2), F3(t3, t4, t5), fmaxf(t6, t7));
    }
    {
        const float t0 = F3(sB[0], sB[1], sB[2]),   t1 = F3(sB[3], sB[4], sB[5]);
        const float t2 = F3(sB[6], sB[7], sB[8]),   t3 = F3(sB[9], sB[10], sB[11]);
        const float t4 = F3(sB[12], sB[13], sB[14]), t5 = F3(sB[15], sB[16], sB[17]);
        const float t6 = F3(sB[18], sB[19], sB[20]), t7 = fmaxf(sB[21], sB[22]);
        mB = F3(F3(t0, t1, t2), F3(t3, t4, t5), fmaxf(t6, t7));
    }

    // ---- PV: w = sum_j p_j x_j with unnormalized p = exp2(s - m) <= 1 ----
    __half2 wA[5], wB[5];
    #pragma unroll
    for (int q = 0; q < 5; ++q) { wA[q] = __float2half2_rn(0.f); wB[q] = __float2half2_rn(0.f); }
    float smA0 = 0.f, smA1 = 0.f, smB0 = 0.f, smB1 = 0.f;

    #pragma unroll
    for (int j = 0; j < SEQ; ++j) {
        uint4 q4 = *reinterpret_cast<const uint4*>(&xrow[j][0]);
        unsigned q1 = xrow[j][4];
        const float pA = fastexp2(sA[j] - mA);
        const float pB = fastexp2(sB[j] - mB);
        if (j & 1) { smA1 += pA; smB1 += pB; } else { smA0 += pA; smB0 += pB; }
        const __half2 hA = __float2half2_rn(pA);
        const __half2 hB = __float2half2_rn(pB);
        wA[0] = __hfma2(hA, u2hh(q4.x), wA[0]);
        wA[1] = __hfma2(hA, u2hh(q4.y), wA[1]);
        wA[2] = __hfma2(hA, u2hh(q4.z), wA[2]);
        wA[3] = __hfma2(hA, u2hh(q4.w), wA[3]);
        wA[4] = __hfma2(hA, u2hh(q1),   wA[4]);
        wB[0] = __hfma2(hB, u2hh(q4.x), wB[0]);
        wB[1] = __hfma2(hB, u2hh(q4.y), wB[1]);
        wB[2] = __hfma2(hB, u2hh(q4.z), wB[2]);
        wB[3] = __hfma2(hB, u2hh(q4.w), wB[3]);
        wB[4] = __hfma2(hB, u2hh(q1),   wB[4]);
    }

    const float invA = __builtin_amdgcn_rcpf(smA0 + smA1);
    const float invB = __builtin_amdgcn_rcpf(smB0 + smB1);

    // ---- context via linearity: c = Wv w (scalar weights), fuse norm+residual ----
    float* opA = out + (b * SEQ + rA) * DIM;
    float* opB = out + (b * SEQ + rB) * DIM;
    #pragma unroll
    for (int q = 0; q < 5; ++q) {
        float e0A = 0.f, e1A = 0.f, e0B = 0.f, e1B = 0.f;
        #pragma unroll
        for (int p = 0; p < 5; ++p) {
            const hf2 v0 = u2h(wsu[50 + (2 * q) * 5 + p]);
            const hf2 v1 = u2h(wsu[50 + (2 * q + 1) * 5 + p]);
            e0A = fdot2(h2f(wA[p]), v0, e0A);
            e1A = fdot2(h2f(wA[p]), v1, e1A);
            e0B = fdot2(h2f(wB[p]), v0, e0B);
            e1B = fdot2(h2f(wB[p]), v1, e1B);
        }
        float2 oa, ob;
        oa.x = fmaf(e0A, invA, xrA[2 * q]);
        oa.y = fmaf(e1A, invA, xrA[2 * q + 1]);
        *reinterpret_cast<float2*>(opA + 2 * q) = oa;
        if (hasB) {
            ob.x = fmaf(e0B, invB, xrB[2 * q]);
            ob.y = fmaf(e1B, invB, xrB[2 * q + 1]);
            *reinterpret_cast<float2*>(opB + 2 * q) = ob;
        }
    }
}

extern "C" void kernel_launch(void* const* d_in, const int* in_sizes, int n_in,
                              void* d_out, int out_size, void* d_ws, size_t ws_size,
                              hipStream_t stream) {
    const float* x  = (const float*)d_in[0];
    const float* Wk = (const float*)d_in[1];
    const float* Wq = (const float*)d_in[2];
    const float* Wv = (const float*)d_in[3];
    float* out = (float*)d_out;
    unsigned* ws = (unsigned*)d_ws;

    const int B = in_sizes[0] / (SEQ * DIM);
    hipLaunchKernelGGL(attn_prep_kernel, dim3(1), dim3(128), 0, stream,
                       Wk, Wq, Wv, ws);
    const int blocks = (B + BPB - 1) / BPB;
    hipLaunchKernelGGL(attn_main_kernel, dim3(blocks), dim3(NTHR), 0, stream,
                       x, ws, out, B);
}

// Round 5
// 162.275 us; speedup vs baseline: 2.9346x; 2.9346x over previous
//
#include <hip/hip_runtime.h>
#include <hip/hip_fp16.h>

#define SEQ 23
#define DIM 10
#define TPB 12                 // threads per batch (thread t owns rows t and t+12)
#define BPB 21                 // batches per block (21*12 = 252 of 256 threads)
#define NTHR 256
#define NROW (BPB * SEQ)       // 483 real rows + 1 dummy

typedef _Float16 hf2 __attribute__((ext_vector_type(2)));

static __device__ __forceinline__ float fdot2(hf2 a, hf2 b, float c) {
#if __has_builtin(__builtin_amdgcn_fdot2)
    return __builtin_amdgcn_fdot2(a, b, c, false);
#else
    return c + (float)a[0] * (float)b[0] + (float)a[1] * (float)b[1];
#endif
}
static __device__ __forceinline__ float fastexp2(float x) {
#if __has_builtin(__builtin_amdgcn_exp2f)
    return __builtin_amdgcn_exp2f(x);
#else
    return exp2f(x);
#endif
}
static __device__ __forceinline__ unsigned pack2(float a, float b) {
    __half2 h = __floats2half2_rn(a, b);   // v_cvt_pkrtz_f16_f32
    return __builtin_bit_cast(unsigned, h);
}
static __device__ __forceinline__ hf2 u2h(unsigned u) {
    return __builtin_bit_cast(hf2, u);
}
static __device__ __forceinline__ __half2 u2hh(unsigned u) {
    return __builtin_bit_cast(__half2, u);
}
static __device__ __forceinline__ hf2 h2f(__half2 h) {
    return __builtin_bit_cast(hf2, h);
}

// ---- prep: ws[a*5+p]    = half2(MT[a][2p], MT[a][2p+1]),  MT = sc*(Wq^T Wk)^T
//      ws[50+e*5+p] = half2(Wv[e][2p], Wv[e][2p+1]),  sc = (1/sqrt(10))*log2(e)
__global__ void attn_prep_kernel(const float* __restrict__ Wk,
                                 const float* __restrict__ Wq,
                                 const float* __restrict__ Wv,
                                 unsigned* __restrict__ ws) {
    const int t = threadIdx.x;
    if (t < 50) {
        const int a = t / 5, p = t % 5;
        float m0 = 0.f, m1 = 0.f;
        #pragma unroll
        for (int k = 0; k < 10; ++k) {
            m0 += Wq[k * 10 + 2 * p]     * Wk[k * 10 + a];
            m1 += Wq[k * 10 + 2 * p + 1] * Wk[k * 10 + a];
        }
        const float sc = 0.31622776601683794f * 1.44269504088896340f;
        ws[t] = pack2(m0 * sc, m1 * sc);
    } else if (t < 100) {
        const int e = (t - 50) / 5, p = (t - 50) % 5;
        ws[t] = pack2(Wv[e * 10 + 2 * p], Wv[e * 10 + 2 * p + 1]);
    }
}

__global__ __launch_bounds__(NTHR) void attn_main_kernel(
    const float* __restrict__ x,      // [B][23][10] f32
    const unsigned* __restrict__ wsu, // packed weights (uniform -> s_load)
    float* __restrict__ out,          // [B][230] f32
    int B)
{
    // x rows as f16 pairs, 32B stride (b128 + b32 per row); +1 shared dummy row
    __shared__ __align__(16) unsigned xb[NROW + 1][8];

    const int tid = threadIdx.x;
    const int bl  = tid / TPB;
    const int t   = tid - bl * TPB;
    const long b  = (long)blockIdx.x * BPB + bl;
    const bool act  = (tid < BPB * TPB) && (b < (long)B);
    const bool hasB = act && (t < TPB - 1);   // row t+12 valid only for t<11

    const int rA = t, rB = t + TPB;

    hf2      xpA[5], xpB[5];   // own rows, packed f16 (kept for residual too)
    unsigned upA[5], upB[5];   // u' = MT x, packed f16, in registers

    if (act) {
        const float* pa = x + (b * SEQ + rA) * DIM;
        const float* pb = x + (b * SEQ + (hasB ? rB : rA)) * DIM;
        #pragma unroll
        for (int p = 0; p < 5; ++p) {
            float2 ta = *reinterpret_cast<const float2*>(pa + 2 * p);
            float2 tb = *reinterpret_cast<const float2*>(pb + 2 * p);
            xpA[p] = u2h(pack2(ta.x, ta.y));
            xpB[p] = u2h(pack2(tb.x, tb.y));
        }
        const int rowA = bl * SEQ + rA;
        const int rowB = hasB ? (bl * SEQ + rB) : NROW;
        *reinterpret_cast<uint4*>(&xb[rowA][0]) = make_uint4(
            __builtin_bit_cast(unsigned, xpA[0]), __builtin_bit_cast(unsigned, xpA[1]),
            __builtin_bit_cast(unsigned, xpA[2]), __builtin_bit_cast(unsigned, xpA[3]));
        xb[rowA][4] = __builtin_bit_cast(unsigned, xpA[4]);
        *reinterpret_cast<uint4*>(&xb[rowB][0]) = make_uint4(
            __builtin_bit_cast(unsigned, xpB[0]), __builtin_bit_cast(unsigned, xpB[1]),
            __builtin_bit_cast(unsigned, xpB[2]), __builtin_bit_cast(unsigned, xpB[3]));
        xb[rowB][4] = __builtin_bit_cast(unsigned, xpB[4]);

        // u' projections (scalar-loaded MT), stay in registers
        #pragma unroll
        for (int q = 0; q < 5; ++q) {
            float a0 = 0.f, a1 = 0.f, b0 = 0.f, b1 = 0.f;
            #pragma unroll
            for (int p = 0; p < 5; ++p) {
                const hf2 m0 = u2h(wsu[(2 * q) * 5 + p]);
                const hf2 m1 = u2h(wsu[(2 * q + 1) * 5 + p]);
                a0 = fdot2(xpA[p], m0, a0);
                a1 = fdot2(xpA[p], m1, a1);
                b0 = fdot2(xpB[p], m0, b0);
                b1 = fdot2(xpB[p], m1, b1);
            }
            upA[q] = pack2(a0, a1);
            upB[q] = pack2(b0, b1);
        }
    }
    __syncthreads();
    if (!act) return;

    const unsigned (*xrow)[8] = &xb[bl * SEQ];

    // ---- logits for both rows (log2 units): s[j] = u' . x_j ----
    float sA[SEQ], sB[SEQ];
    #pragma unroll
    for (int j = 0; j < SEQ; ++j) {
        uint4 q4 = *reinterpret_cast<const uint4*>(&xrow[j][0]);
        unsigned q1 = xrow[j][4];
        float a = fdot2(u2h(upA[0]), u2h(q4.x), 0.f);
        a = fdot2(u2h(upA[1]), u2h(q4.y), a);
        a = fdot2(u2h(upA[2]), u2h(q4.z), a);
        a = fdot2(u2h(upA[3]), u2h(q4.w), a);
        a = fdot2(u2h(upA[4]), u2h(q1),   a);
        sA[j] = a;
        float c = fdot2(u2h(upB[0]), u2h(q4.x), 0.f);
        c = fdot2(u2h(upB[1]), u2h(q4.y), c);
        c = fdot2(u2h(upB[2]), u2h(q4.z), c);
        c = fdot2(u2h(upB[3]), u2h(q4.w), c);
        c = fdot2(u2h(upB[4]), u2h(q1),   c);
        sB[j] = c;
    }

    // ---- max via 3-way trees (v_max3_f32) ----
#define F3(a, b, c) fmaxf(fmaxf((a), (b)), (c))
    float mA, mB;
    {
        const float t0 = F3(sA[0], sA[1], sA[2]),   t1 = F3(sA[3], sA[4], sA[5]);
        const float t2 = F3(sA[6], sA[7], sA[8]),   t3 = F3(sA[9], sA[10], sA[11]);
        const float t4 = F3(sA[12], sA[13], sA[14]), t5 = F3(sA[15], sA[16], sA[17]);
        const float t6 = F3(sA[18], sA[19], sA[20]), t7 = fmaxf(sA[21], sA[22]);
        mA = F3(F3(t0, t1, t2), F3(t3, t4, t5), fmaxf(t6, t7));
    }
    {
        const float t0 = F3(sB[0], sB[1], sB[2]),   t1 = F3(sB[3], sB[4], sB[5]);
        const float t2 = F3(sB[6], sB[7], sB[8]),   t3 = F3(sB[9], sB[10], sB[11]);
        const float t4 = F3(sB[12], sB[13], sB[14]), t5 = F3(sB[15], sB[16], sB[17]);
        const float t6 = F3(sB[18], sB[19], sB[20]), t7 = fmaxf(sB[21], sB[22]);
        mB = F3(F3(t0, t1, t2), F3(t3, t4, t5), fmaxf(t6, t7));
    }

    // ---- PV: w = sum_j p_j x_j, unnormalized p = exp2(s - m) <= 1 ----
    __half2 wA[5], wB[5];
    #pragma unroll
    for (int q = 0; q < 5; ++q) { wA[q] = __float2half2_rn(0.f); wB[q] = __float2half2_rn(0.f); }
    float smA0 = 0.f, smA1 = 0.f, smB0 = 0.f, smB1 = 0.f;

    #pragma unroll
    for (int j = 0; j < SEQ; ++j) {
        uint4 q4 = *reinterpret_cast<const uint4*>(&xrow[j][0]);
        unsigned q1 = xrow[j][4];
        const float pA = fastexp2(sA[j] - mA);
        const float pB = fastexp2(sB[j] - mB);
        if (j & 1) { smA1 += pA; smB1 += pB; } else { smA0 += pA; smB0 += pB; }
        const __half2 hA = __float2half2_rn(pA);
        const __half2 hB = __float2half2_rn(pB);
        wA[0] = __hfma2(hA, u2hh(q4.x), wA[0]);
        wA[1] = __hfma2(hA, u2hh(q4.y), wA[1]);
        wA[2] = __hfma2(hA, u2hh(q4.z), wA[2]);
        wA[3] = __hfma2(hA, u2hh(q4.w), wA[3]);
        wA[4] = __hfma2(hA, u2hh(q1),   wA[4]);
        wB[0] = __hfma2(hB, u2hh(q4.x), wB[0]);
        wB[1] = __hfma2(hB, u2hh(q4.y), wB[1]);
        wB[2] = __hfma2(hB, u2hh(q4.z), wB[2]);
        wB[3] = __hfma2(hB, u2hh(q4.w), wB[3]);
        wB[4] = __hfma2(hB, u2hh(q1),   wB[4]);
    }

    const float invA = __builtin_amdgcn_rcpf(smA0 + smA1);
    const float invB = __builtin_amdgcn_rcpf(smB0 + smB1);

    // ---- context c = Wv w (scalar weights); fuse normalize + residual ----
    float* opA = out + (b * SEQ + rA) * DIM;
    float* opB = out + (b * SEQ + rB) * DIM;
    #pragma unroll
    for (int q = 0; q < 5; ++q) {
        float e0A = 0.f, e1A = 0.f, e0B = 0.f, e1B = 0.f;
        #pragma unroll
        for (int p = 0; p < 5; ++p) {
            const hf2 v0 = u2h(wsu[50 + (2 * q) * 5 + p]);
            const hf2 v1 = u2h(wsu[50 + (2 * q + 1) * 5 + p]);
            e0A = fdot2(h2f(wA[p]), v0, e0A);
            e1A = fdot2(h2f(wA[p]), v1, e1A);
            e0B = fdot2(h2f(wB[p]), v0, e0B);
            e1B = fdot2(h2f(wB[p]), v1, e1B);
        }
        float2 oa;
        oa.x = fmaf(e0A, invA, (float)xpA[q][0]);
        oa.y = fmaf(e1A, invA, (float)xpA[q][1]);
        *reinterpret_cast<float2*>(opA + 2 * q) = oa;
        if (hasB) {
            float2 ob;
            ob.x = fmaf(e0B, invB, (float)xpB[q][0]);
            ob.y = fmaf(e1B, invB, (float)xpB[q][1]);
            *reinterpret_cast<float2*>(opB + 2 * q) = ob;
        }
    }
}

extern "C" void kernel_launch(void* const* d_in, const int* in_sizes, int n_in,
                              void* d_out, int out_size, void* d_ws, size_t ws_size,
                              hipStream_t stream) {
    const float* x  = (const float*)d_in[0];
    const float* Wk = (const float*)d_in[1];
    const float* Wq = (const float*)d_in[2];
    const float* Wv = (const float*)d_in[3];
    float* out = (float*)d_out;
    unsigned* ws = (unsigned*)d_ws;

    const int B = in_sizes[0] / (SEQ * DIM);
    hipLaunchKernelGGL(attn_prep_kernel, dim3(1), dim3(128), 0, stream,
                       Wk, Wq, Wv, ws);
    const int blocks = (B + BPB - 1) / BPB;
    hipLaunchKernelGGL(attn_main_kernel, dim3(blocks), dim3(NTHR), 0, stream,
                       x, ws, out, B);
}